// Round 3
// baseline (107.789 us; speedup 1.0000x reference)
//
#include <hip/hip_runtime.h>
#include <hip/hip_fp16.h>
#include <math.h>

namespace {
constexpr int kNB  = 16;
constexpr int kNA  = 1024;
constexpr int kP   = 65536;           // pairs per batch (power of 2)
constexpr int kNW  = 8;               // NWAVE
constexpr int kTot = kNB * kNA;       // 16384 atoms
constexpr int kMaxNei = 128;          // bucket capacity (mean 64, sigma 8)
constexpr float kInvCut = 1.0f / 6.0f;
constexpr float kPi = 3.14159265358979323846f;

constexpr int kBuildThreads = 512;    // threads per build block
constexpr int kPairsPerThr  = 4;      // CONSECUTIVE pairs per thread
constexpr int kChunkPairs   = kBuildThreads * kPairsPerThr;  // 2048
constexpr int kChunksPerB   = kP / kChunkPairs;              // 32

typedef int   int4v   __attribute__((ext_vector_type(4)));
typedef float float4v __attribute__((ext_vector_type(4)));
}

// Phase A: chunk-histogram slot reservation.
// Round-3 changes: (1) each thread owns 4 CONSECUTIVE pairs so the pass-1
// input reads are 2x int4 + 3x float4 (5 wide loads vs 20 scalar dwords --
// 4x fewer VMEM instructions, same bytes); (2) 2048-pair chunks / 512
// threads -> 512 blocks = 2 blocks/CU, so one block's scatter pass overlaps
// the other's load pass across the barriers (round 2 had exactly 1 block/CU,
// serializing the whole CU at every __syncthreads).
__global__ __launch_bounds__(kBuildThreads) void build_lists(
    const float* __restrict__ coords,   // [Tot*3]
    const int*   __restrict__ aidx,     // [NB*2*P]
    const float* __restrict__ shifts,   // [NB*P*3]
    int*   __restrict__ cnt,            // [Tot]
    uint4* __restrict__ lists)          // [Tot*kMaxNei], 16 B payloads
{
  __shared__ int hist[kNA];             // pass1: counts; pass2+: bases

  const int tid = threadIdx.x;
  const int r = blockIdx.x & 7;                  // XCD slot
  const int q = blockIdx.x >> 3;                 // 0..63
  const int b = r + ((q >> 5) << 3);             // batch: r or r+8
  const int chunk = q & (kChunksPerB - 1);       // chunk within batch
  const int p0 = chunk * kChunkPairs + tid * kPairsPerThr;

  hist[tid] = 0; hist[tid + 512] = 0;
  __syncthreads();

  // Pass 1: wide loads, per-pair geometry, LDS-rank reservation.
  const int4v i0v = __builtin_nontemporal_load(
      (const int4v*)&aidx[(b * 2 + 0) * kP + p0]);
  const int4v i1v = __builtin_nontemporal_load(
      (const int4v*)&aidx[(b * 2 + 1) * kP + p0]);
  const float* sp = &shifts[(size_t)(b * kP + p0) * 3];
  const float4v s0 = __builtin_nontemporal_load((const float4v*)(sp + 0));
  const float4v s1 = __builtin_nontemporal_load((const float4v*)(sp + 4));
  const float4v s2 = __builtin_nontemporal_load((const float4v*)(sp + 8));
  float sflat[12] = {s0.x, s0.y, s0.z, s0.w, s1.x, s1.y, s1.z, s1.w,
                     s2.x, s2.y, s2.z, s2.w};

  uint4    pay[kPairsPerThr];
  unsigned meta[kPairsPerThr];           // bit31=active | rank<<10 | i0

#pragma unroll
  for (int it = 0; it < kPairsPerThr; ++it) {
    const int i0 = ((const int*)&i0v)[it];
    const int i1 = ((const int*)&i1v)[it];
    const int gi = b * kNA + i0;
    const int gj = b * kNA + i1;

    const float sx = sflat[it * 3 + 0];
    const float sy = sflat[it * 3 + 1];
    const float sz = sflat[it * 3 + 2];
    const bool valid = (sx > -1.0e9f) & (sy > -1.0e9f) & (sz > -1.0e9f);

    const float dx = coords[gi * 3 + 0] - coords[gj * 3 + 0] + sx;
    const float dy = coords[gi * 3 + 1] - coords[gj * 3 + 1] + sy;
    const float dz = coords[gi * 3 + 2] - coords[gj * 3 + 2] + sz;

    const float dist = sqrtf(dx * dx + dy * dy + dz * dz);
    const float rr = dist * kInvCut;
    float f = 0.5f * (__cosf(kPi * fminf(rr, 1.0f)) + 1.0f);
    if (!valid | (rr >= 1.0f)) f = 0.0f;

    unsigned m = 0u;
    if (f != 0.0f) {
      const int rank = atomicAdd(&hist[i0], 1);   // LDS atomic: cheap
      m = 0x80000000u | ((unsigned)rank << 10) | (unsigned)i0;
      const float inv = (dist > 1e-12f) ? (1.0f / dist) : 1.0f;
      const float ux = dx * inv, uy = dy * inv, uz = dz * inv;
      pay[it].x = __builtin_bit_cast(unsigned, dist);
      pay[it].y = __builtin_bit_cast(unsigned, f);
      pay[it].z = __builtin_bit_cast(unsigned, __floats2half2_rn(ux, uy));
      pay[it].w = __builtin_bit_cast(unsigned, __floats2half2_rn(uz, 0.0f));
    }
    meta[it] = m;
  }
  __syncthreads();

  // Pass 2: one global atomic per touched atom reserves the bucket range.
#pragma unroll
  for (int t = tid; t < kNA; t += kBuildThreads) {
    const int c = hist[t];
    if (c > 0) hist[t] = atomicAdd(&cnt[b * kNA + t], c);
  }
  __syncthreads();

  // Pass 3: scatter 16 B payloads at base + rank. The ~2 entries an atom
  // gets per chunk are contiguous -> L2 write-merging into full lines.
#pragma unroll
  for (int it = 0; it < kPairsPerThr; ++it) {
    const unsigned m = meta[it];
    if (m & 0x80000000u) {
      const int lid  = (int)(m & 1023u);
      const int rank = (int)((m >> 10) & 0xFFFu);
      const int pos  = hist[lid] + rank;
      if (pos < kMaxNei) {
        lists[(size_t)(b * kNA + lid) * kMaxNei + pos] = pay[it];
      }
    }
  }
}

// Phase B: 32 threads per atom (k = contiguous quarter-slice 0..3, w = wave
// channel 0..7). Payload carries finished geometry, so the inner loop is
// {unpack, dr, exp, fr, 13 fma} -- near the VALU floor (~3 us). Unchanged.
__global__ __launch_bounds__(256) void gather_density(
    const uint4* __restrict__ lists,    // [Tot*kMaxNei]
    const int*   __restrict__ cnt,      // [Tot]
    const int*   __restrict__ species,  // [Tot]
    const float* __restrict__ rs,       // [NTYPE*NWAVE]
    const float* __restrict__ inta,     // [NTYPE*NWAVE]
    const float* __restrict__ params,   // [NTYPE]
    float* __restrict__ out)            // [Tot*24]
{
  const int r = blockIdx.x & 7;
  const int m = blockIdx.x >> 3;                 // 0..255
  const int b = r + ((m >> 7) << 3);             // batch: r or r+8
  const int g = m & 127;                         // atom octet within batch
  const int i = b * kNA + g * 8 + (threadIdx.x >> 5);
  const int k = (threadIdx.x >> 3) & 3;          // quarter-slice
  const int w = threadIdx.x & 7;                 // wave channel

  const int s = species[i];
  const float rsw   = rs[s * kNW + w];
  const float intaw = inta[s * kNW + w];
  const int n = min(cnt[i], kMaxNei);
  const int Q = (n + 3) >> 2;                    // balanced slice length
  const int j0 = k * Q;                          // j0+Q-1 <= 127 always
  const uint4* __restrict__ L = lists + (size_t)i * kMaxNei;

  float a[13];
#pragma unroll
  for (int mm = 0; mm < 13; ++mm) a[mm] = 0.0f;

#pragma unroll 4
  for (int t = 0; t < Q; ++t) {
    const int j = j0 + t;
    const uint4 u = L[j];                        // safe: j < kMaxNei
    if (j < n) {                                 // predicate: slots >= n hold
      const float dist = __builtin_bit_cast(float, u.x);   // poison garbage
      const float f    = __builtin_bit_cast(float, u.y);
      const float2 uxy = __half22float2(__builtin_bit_cast(__half2, u.z));
      const float2 uzp = __half22float2(__builtin_bit_cast(__half2, u.w));
      const float ux = uxy.x, uy = uxy.y, uz = uzp.x;
      const float dr = dist - rsw;
      const float rad = __expf(-intaw * dr * dr);
      const float fr = f * rad;
      a[0] += fr;
      const float rx = fr * ux, ry = fr * uy, rz = fr * uz;
      a[1] += rx;        a[2] += ry;        a[3] += rz;
      a[4] += rx * ux;   a[5] += rx * uy;   a[6] += rx * uz;
      a[7] += ry * ux;   a[8] += ry * uy;   a[9] += ry * uz;
      a[10] += rz * ux;  a[11] += rz * uy;  a[12] += rz * uz;
    }
  }

  // Reduce across the 4 k-slices (lanes differing in bits 3..4).
#pragma unroll
  for (int mm = 0; mm < 13; ++mm) {
    a[mm] += __shfl_xor(a[mm], 8);
    a[mm] += __shfl_xor(a[mm], 16);
  }

  if (k == 0) {
    const float pm = params[s];
    const float o0 = a[0] * a[0];
    const float o1 = a[1] * a[1] + a[2] * a[2] + a[3] * a[3];
    const float o2 = a[4] * a[4] + a[5] * a[5] + a[6] * a[6] +
                     a[7] * a[7] + a[8] * a[8] + a[9] * a[9] +
                     a[10] * a[10] + a[11] * a[11] + a[12] * a[12];
    float* o = out + (size_t)i * 24;
    o[0 * kNW + w] = pm * o0;
    o[1 * kNW + w] = pm * o1;
    o[2 * kNW + w] = pm * o2;
  }
}

extern "C" void kernel_launch(void* const* d_in, const int* in_sizes, int n_in,
                              void* d_out, int out_size, void* d_ws, size_t ws_size,
                              hipStream_t stream) {
  const float* coords  = (const float*)d_in[0];  // (16,1024,3)
  const int*   aidx    = (const int*)d_in[2];    // (16,2,65536)
  const float* shifts  = (const float*)d_in[3];  // (16,65536,3)
  const int*   species = (const int*)d_in[4];    // (16384,)
  const float* rs      = (const float*)d_in[5];  // (4,8)
  const float* inta    = (const float*)d_in[6];  // (4,8)
  const float* params  = (const float*)d_in[7];  // (4,)
  float* out = (float*)d_out;                    // (16384, 24)

  // Workspace: [cnt: 16384 int = 64 KB][lists: 16384*128 uint4 = 32 MB]
  int*   cnt   = (int*)d_ws;
  uint4* lists = (uint4*)((char*)d_ws + (size_t)kTot * sizeof(int));

  hipMemsetAsync(cnt, 0, (size_t)kTot * sizeof(int), stream);

  const int nblocks = kNB * kChunksPerB;         // 512 blocks
  build_lists<<<nblocks, kBuildThreads, 0, stream>>>(coords, aidx, shifts,
                                                     cnt, lists);
  gather_density<<<(kTot * 32) / 256, 256, 0, stream>>>(lists, cnt, species,
                                                        rs, inta, params, out);
}

// Round 4
// 105.906 us; speedup vs baseline: 1.0178x; 1.0178x over previous
//
#include <hip/hip_runtime.h>
#include <hip/hip_fp16.h>
#include <math.h>

namespace {
constexpr int kNB  = 16;
constexpr int kNA  = 1024;
constexpr int kP   = 65536;           // pairs per batch (power of 2)
constexpr int kNW  = 8;               // NWAVE
constexpr int kTot = kNB * kNA;       // 16384 atoms
constexpr int kMaxNei = 128;          // bucket capacity (mean 64, sigma 8)
constexpr float kInvCut = 1.0f / 6.0f;
constexpr float kPi = 3.14159265358979323846f;

constexpr int kBuildThreads = 1024;   // threads per build block
constexpr int kPerThread = 4;         // pairs per thread, STRIDED by 1024
constexpr int kChunkPairs = kBuildThreads * kPerThread;  // 4096
constexpr int kChunksPerB = kP / kChunkPairs;            // 16
}

// Phase A: chunk-histogram slot reservation + LDS re-sort before scatter.
// Base = round-2 structure (1024 thr, strided pairs: proven 105.3 us total).
// New: pass 3 stages payloads in LDS in (atom, rank) order, then copies
// linearly to global. An atom's 4-slot 64 B bucket line was previously
// written by ~4 different waves at different times (partial-line dirty
// evictions -> HBM read-modify-write on ~16 MB). Now adjacent lanes of one
// wave write adjacent destinations -> full-line merged writes, no RMW.
__global__ __launch_bounds__(kBuildThreads) void build_lists(
    const float* __restrict__ coords,   // [Tot*3]
    const int*   __restrict__ aidx,     // [NB*2*P]
    const float* __restrict__ shifts,   // [NB*P*3]
    int*   __restrict__ cnt,            // [Tot]
    uint4* __restrict__ lists)          // [Tot*kMaxNei], 16 B payloads
{
  __shared__ int   hist[kNA];           // pass1: counts; pass2b+: global base
  __shared__ int   ofs[kNA];            // exclusive scan (staging offset)
  __shared__ int   wsum[16];            // per-wave scan partials
  __shared__ int   totalS;
  __shared__ uint4 stage[kChunkPairs];  // 64 KB staging, (atom,rank)-sorted

  const int tid = threadIdx.x;
  const int r = blockIdx.x & 7;                  // XCD slot
  const int q = blockIdx.x >> 3;                 // 0..31
  const int b = r + ((q >> 4) << 3);             // batch: r or r+8
  const int chunk = q & (kChunksPerB - 1);       // chunk within batch
  const int pairBase = chunk * kChunkPairs;

  hist[tid] = 0;
  __syncthreads();

  uint4    pay[kPerThread];
  unsigned meta[kPerThread];             // bit31=active | rank<<10 | i0

  // Pass 1: coalesced loads (lane i, iter it -> pair pairBase+it*1024+i),
  // per-pair geometry, LDS-rank reservation.
#pragma unroll
  for (int it = 0; it < kPerThread; ++it) {
    const int p = pairBase + it * kBuildThreads + tid;

    const int i0 = __builtin_nontemporal_load(&aidx[(b * 2 + 0) * kP + p]);
    const int i1 = __builtin_nontemporal_load(&aidx[(b * 2 + 1) * kP + p]);
    const int gi = b * kNA + i0;
    const int gj = b * kNA + i1;

    const size_t sb = (size_t)(b * kP + p) * 3;
    const float sx = __builtin_nontemporal_load(&shifts[sb + 0]);
    const float sy = __builtin_nontemporal_load(&shifts[sb + 1]);
    const float sz = __builtin_nontemporal_load(&shifts[sb + 2]);
    const bool valid = (sx > -1.0e9f) & (sy > -1.0e9f) & (sz > -1.0e9f);

    const float dx = coords[gi * 3 + 0] - coords[gj * 3 + 0] + sx;
    const float dy = coords[gi * 3 + 1] - coords[gj * 3 + 1] + sy;
    const float dz = coords[gi * 3 + 2] - coords[gj * 3 + 2] + sz;

    const float dist = sqrtf(dx * dx + dy * dy + dz * dz);
    const float rr = dist * kInvCut;
    float f = 0.5f * (__cosf(kPi * fminf(rr, 1.0f)) + 1.0f);
    if (!valid | (rr >= 1.0f)) f = 0.0f;

    unsigned m = 0u;
    if (f != 0.0f) {
      const int rank = atomicAdd(&hist[i0], 1);   // LDS atomic: cheap
      m = 0x80000000u | ((unsigned)rank << 10) | (unsigned)i0;
      const float inv = (dist > 1e-12f) ? (1.0f / dist) : 1.0f;
      const float ux = dx * inv, uy = dy * inv, uz = dz * inv;
      pay[it].x = __builtin_bit_cast(unsigned, dist);
      pay[it].y = __builtin_bit_cast(unsigned, f);
      pay[it].z = __builtin_bit_cast(unsigned, __floats2half2_rn(ux, uy));
      pay[it].w = __builtin_bit_cast(unsigned, __floats2half2_rn(uz, 0.0f));
    }
    meta[it] = m;
  }
  __syncthreads();

  // Pass 2a: exclusive prefix sum of hist -> ofs (2-level wave scan).
  const int lane = tid & 63;
  const int wv   = tid >> 6;                     // 16 waves
  const int selfc = hist[tid];
  int val = selfc;
#pragma unroll
  for (int o = 1; o < 64; o <<= 1) {
    const int t = __shfl_up(val, o);
    if (lane >= o) val += t;
  }
  if (lane == 63) wsum[wv] = val;
  __syncthreads();
  if (wv == 0) {
    int wval = (lane < 16) ? wsum[lane] : 0;
#pragma unroll
    for (int o = 1; o < 16; o <<= 1) {
      const int t = __shfl_up(wval, o);
      if (lane >= o) wval += t;
    }
    if (lane < 16) wsum[lane] = wval;            // inclusive wave totals
    if (lane == 15) totalS = wval;
  }
  __syncthreads();
  const int wbase = (wv == 0) ? 0 : wsum[wv - 1];
  ofs[tid] = wbase + val - selfc;                // exclusive offset

  // Pass 2b: one global atomic per touched atom reserves the bucket range.
  int base = 0;
  if (selfc > 0) base = atomicAdd(&cnt[b * kNA + tid], selfc);
  hist[tid] = base;                              // own-slot overwrite
  __syncthreads();

  // Pass 3a: stage payloads at ofs[atom]+rank; pack atom id into the spare
  // high half of .w (gather reads only the low half = uz).
#pragma unroll
  for (int it = 0; it < kPerThread; ++it) {
    const unsigned m = meta[it];
    if (m & 0x80000000u) {
      const int lid  = (int)(m & 1023u);
      const int rank = (int)((m >> 10) & 0xFFFu);
      uint4 u = pay[it];
      u.w = (u.w & 0xFFFFu) | ((unsigned)lid << 16);
      stage[ofs[lid] + rank] = u;
    }
  }
  __syncthreads();

  // Pass 3b: linear copy stage -> lists. Consecutive lanes hit consecutive
  // destinations (atom-major sorted) -> full-line merged global writes.
  const int T = totalS;
  for (int t = tid; t < T; t += kBuildThreads) {
    const uint4 u = stage[t];
    const int a    = (int)(u.w >> 16);
    const int rank = t - ofs[a];
    const int pos  = hist[a] + rank;
    if (pos < kMaxNei) {
      lists[(size_t)(b * kNA + a) * kMaxNei + pos] = u;
    }
  }
}

// Phase B: unchanged (proven round 2/3). 32 threads per atom (k = contiguous
// quarter-slice 0..3, w = wave channel 0..7). Payload carries finished
// geometry; inner loop is {unpack, dr, exp, fr, 13 fma}.
__global__ __launch_bounds__(256) void gather_density(
    const uint4* __restrict__ lists,    // [Tot*kMaxNei]
    const int*   __restrict__ cnt,      // [Tot]
    const int*   __restrict__ species,  // [Tot]
    const float* __restrict__ rs,       // [NTYPE*NWAVE]
    const float* __restrict__ inta,     // [NTYPE*NWAVE]
    const float* __restrict__ params,   // [NTYPE]
    float* __restrict__ out)            // [Tot*24]
{
  const int r = blockIdx.x & 7;
  const int m = blockIdx.x >> 3;                 // 0..255
  const int b = r + ((m >> 7) << 3);             // batch: r or r+8
  const int g = m & 127;                         // atom octet within batch
  const int i = b * kNA + g * 8 + (threadIdx.x >> 5);
  const int k = (threadIdx.x >> 3) & 3;          // quarter-slice
  const int w = threadIdx.x & 7;                 // wave channel

  const int s = species[i];
  const float rsw   = rs[s * kNW + w];
  const float intaw = inta[s * kNW + w];
  const int n = min(cnt[i], kMaxNei);
  const int Q = (n + 3) >> 2;                    // balanced slice length
  const int j0 = k * Q;                          // j0+Q-1 <= 127 always
  const uint4* __restrict__ L = lists + (size_t)i * kMaxNei;

  float a[13];
#pragma unroll
  for (int mm = 0; mm < 13; ++mm) a[mm] = 0.0f;

#pragma unroll 4
  for (int t = 0; t < Q; ++t) {
    const int j = j0 + t;
    const uint4 u = L[j];                        // safe: j < kMaxNei
    if (j < n) {                                 // predicate: slots >= n hold
      const float dist = __builtin_bit_cast(float, u.x);   // poison garbage
      const float f    = __builtin_bit_cast(float, u.y);
      const float2 uxy = __half22float2(__builtin_bit_cast(__half2, u.z));
      const float2 uzp = __half22float2(__builtin_bit_cast(__half2, u.w));
      const float ux = uxy.x, uy = uxy.y, uz = uzp.x;
      const float dr = dist - rsw;
      const float rad = __expf(-intaw * dr * dr);
      const float fr = f * rad;
      a[0] += fr;
      const float rx = fr * ux, ry = fr * uy, rz = fr * uz;
      a[1] += rx;        a[2] += ry;        a[3] += rz;
      a[4] += rx * ux;   a[5] += rx * uy;   a[6] += rx * uz;
      a[7] += ry * ux;   a[8] += ry * uy;   a[9] += ry * uz;
      a[10] += rz * ux;  a[11] += rz * uy;  a[12] += rz * uz;
    }
  }

  // Reduce across the 4 k-slices (lanes differing in bits 3..4).
#pragma unroll
  for (int mm = 0; mm < 13; ++mm) {
    a[mm] += __shfl_xor(a[mm], 8);
    a[mm] += __shfl_xor(a[mm], 16);
  }

  if (k == 0) {
    const float pm = params[s];
    const float o0 = a[0] * a[0];
    const float o1 = a[1] * a[1] + a[2] * a[2] + a[3] * a[3];
    const float o2 = a[4] * a[4] + a[5] * a[5] + a[6] * a[6] +
                     a[7] * a[7] + a[8] * a[8] + a[9] * a[9] +
                     a[10] * a[10] + a[11] * a[11] + a[12] * a[12];
    float* o = out + (size_t)i * 24;
    o[0 * kNW + w] = pm * o0;
    o[1 * kNW + w] = pm * o1;
    o[2 * kNW + w] = pm * o2;
  }
}

extern "C" void kernel_launch(void* const* d_in, const int* in_sizes, int n_in,
                              void* d_out, int out_size, void* d_ws, size_t ws_size,
                              hipStream_t stream) {
  const float* coords  = (const float*)d_in[0];  // (16,1024,3)
  const int*   aidx    = (const int*)d_in[2];    // (16,2,65536)
  const float* shifts  = (const float*)d_in[3];  // (16,65536,3)
  const int*   species = (const int*)d_in[4];    // (16384,)
  const float* rs      = (const float*)d_in[5];  // (4,8)
  const float* inta    = (const float*)d_in[6];  // (4,8)
  const float* params  = (const float*)d_in[7];  // (4,)
  float* out = (float*)d_out;                    // (16384, 24)

  // Workspace: [cnt: 16384 int = 64 KB][lists: 16384*128 uint4 = 32 MB]
  int*   cnt   = (int*)d_ws;
  uint4* lists = (uint4*)((char*)d_ws + (size_t)kTot * sizeof(int));

  hipMemsetAsync(cnt, 0, (size_t)kTot * sizeof(int), stream);

  const int nblocks = kNB * kChunksPerB;         // 256 blocks
  build_lists<<<nblocks, kBuildThreads, 0, stream>>>(coords, aidx, shifts,
                                                     cnt, lists);
  gather_density<<<(kTot * 32) / 256, 256, 0, stream>>>(lists, cnt, species,
                                                        rs, inta, params, out);
}